// Round 12
// baseline (366.874 us; speedup 1.0000x reference)
//
#include <hip/hip_runtime.h>

#define NN 50000
#define EE 800000
#define DD 128
#define RR 8
#define CELLS (NN * RR)            // 400000 (rel, dst) cells, key = rel*NN + dst (REL-MAJOR)
#define TILE_N 64
#define NBLK ((NN + TILE_N - 1) / TILE_N)          // 782
#define GNB (2 * NBLK)             // 1564 gather blocks per relation (32 nodes each)
#define SCAN_CHUNK 1024
#define SCAN_BLOCKS ((CELLS + SCAN_CHUNK - 1) / SCAN_CHUNK)   // 391

typedef __attribute__((ext_vector_type(4))) float f32x4;
typedef __attribute__((ext_vector_type(8))) short s16x8;
typedef __attribute__((ext_vector_type(4))) unsigned int u32x4;   // nontemporal-safe
union ABu { uint4 q; s16x8 v; };

// ---------------- bf16 helpers ----------------

__device__ __forceinline__ unsigned int packbf2(float a, float b) {
    unsigned int ua = __float_as_uint(a);
    unsigned int ub = __float_as_uint(b);
    ua = (ua + 0x7fffu + ((ua >> 16) & 1u)) >> 16;           // RNE, low half
    ub = (ub + 0x7fffu + ((ub >> 16) & 1u)) & 0xffff0000u;   // RNE, high half
    return ua | ub;
}

// unpack 1 uint4 (8 bf16) and add into sA[0..7]
__device__ __forceinline__ void upadd8(float* sA, uint4 a) {
    unsigned int u[4] = {a.x, a.y, a.z, a.w};
#pragma unroll
    for (int j = 0; j < 4; ++j) {
        sA[2 * j]     += __uint_as_float(u[j] << 16);
        sA[2 * j + 1] += __uint_as_float(u[j] & 0xffff0000u);
    }
}

// ---------------- fused prep: to_bf16 + wpack + rpack + count_cells ----------------
#define NB_A ((NN * 32 + 255) / 256)    // 6250: x -> packed bf16 (float4 -> uint2)
#define NB_B 128                        // wpack: 32768 items
#define NB_C 32                         // rpack: 8192 items
#define NB_D ((EE + 255) / 256)         // 3125: count_cells

__global__ void prep_fused(const float* __restrict__ x, unsigned int* __restrict__ xb,
                           const float* __restrict__ W1, const float* __restrict__ W2,
                           unsigned int* __restrict__ Wb1, unsigned int* __restrict__ Wb2,
                           const float* __restrict__ r1, const float* __restrict__ r2,
                           unsigned int* __restrict__ rb1, unsigned int* __restrict__ rb2,
                           const int* __restrict__ dst, const int* __restrict__ et,
                           int* __restrict__ cnt) {
    int bid = blockIdx.x, tid = threadIdx.x;
    if (bid < NB_A) {
        int i = bid * 256 + tid;
        if (i < NN * 32) {
            float4 v = ((const float4*)x)[i];
            ((uint2*)xb)[i] = make_uint2(packbf2(v.x, v.y), packbf2(v.z, v.w));
        }
    } else if (bid < NB_A + NB_B) {
        // W [16 blocks of 64x64, row-major (k,n)] -> Wb [block][n][kp]
        int i = (bid - NB_A) * 256 + tid;
        int n = i & 63, kp = (i >> 6) & 31, rb = i >> 11;
        int s0 = (rb * 64 + 2 * kp) * 64 + n;
        int s1 = (rb * 64 + 2 * kp + 1) * 64 + n;
        Wb1[((rb * 64 + n) * 32) + kp] = packbf2(W1[s0], W1[s1]);
        Wb2[((rb * 64 + n) * 32) + kp] = packbf2(W2[s0], W2[s1]);
    } else if (bid < NB_A + NB_B + NB_C) {
        // root [128k x 128n] -> rb [n][kp]
        int i = (bid - NB_A - NB_B) * 256 + tid;
        int n = i & 127, kp = i >> 7;
        int s0 = (2 * kp) * 128 + n, s1 = (2 * kp + 1) * 128 + n;
        rb1[n * 64 + kp] = packbf2(r1[s0], r1[s1]);
        rb2[n * 64 + kp] = packbf2(r2[s0], r2[s1]);
    } else {
        int e = (bid - NB_A - NB_B - NB_C) * 256 + tid;
        if (e < EE) atomicAdd(&cnt[et[e] * NN + dst[e]], 1);
    }
}

// ---------------- prep: scans + scatter (CSR by cell = rel*NN + dst) ----------------

__global__ __launch_bounds__(256) void scan1(const int* __restrict__ cnt,
                                             int* __restrict__ off, int* __restrict__ bsum) {
    __shared__ int s[256];
    int tid = threadIdx.x;
    int base = blockIdx.x * SCAN_CHUNK + tid * 4;
    int v[4];
#pragma unroll
    for (int i = 0; i < 4; ++i) v[i] = (base + i < CELLS) ? cnt[base + i] : 0;
    int tot = v[0] + v[1] + v[2] + v[3];
    s[tid] = tot;
    __syncthreads();
    for (int d = 1; d < 256; d <<= 1) {
        int t = (tid >= d) ? s[tid - d] : 0;
        __syncthreads();
        s[tid] += t;
        __syncthreads();
    }
    int excl = s[tid] - tot;
    if (tid == 255) bsum[blockIdx.x] = s[255];
    int run = excl;
#pragma unroll
    for (int i = 0; i < 4; ++i) {
        if (base + i < CELLS) off[base + i] = run;
        run += v[i];
    }
}

// merged scan2+scan3: each block reduces its own chunk-prefix from bsum, then finalizes
__global__ __launch_bounds__(256) void scan3(int* __restrict__ off, const int* __restrict__ bsum,
                                             int* __restrict__ cur) {
    __shared__ int red[256];
    int tid = threadIdx.x, bid = blockIdx.x;
    int a = 0;
    for (int i = tid; i < bid; i += 256) a += bsum[i];
    red[tid] = a;
    __syncthreads();
#pragma unroll
    for (int d = 128; d > 0; d >>= 1) {
        if (tid < d) red[tid] += red[tid + d];
        __syncthreads();
    }
    int add = red[0];
    int base = bid * SCAN_CHUNK + tid * 4;
#pragma unroll
    for (int i = 0; i < 4; ++i) {
        int c = base + i;
        if (c < CELLS) {
            int o = off[c] + add;
            off[c] = o;
            cur[c] = o;
        }
    }
    if (bid == 0 && tid == 0) off[CELLS] = EE;   // sentinel
}

// nontemporal esrc store: bypass L2 so randomly-scattered 4B writes don't ping-pong
// dirty lines between XCD L2s (R10: 54MB write-back for 3.2MB payload).
__global__ void cell_scatter(const int* __restrict__ src, const int* __restrict__ dst,
                             const int* __restrict__ et, int* __restrict__ cur,
                             int* __restrict__ esrc) {
    int e = blockIdx.x * blockDim.x + threadIdx.x;
    if (e < EE) {
        int cell = et[e] * NN + dst[e];
        int pos = atomicAdd(&cur[cell], 1);
        __builtin_nontemporal_store(src[e], &esrc[pos]);
    }
}

// ---------------- standalone gather v3: 16-lane-group-per-node ----------------
// R10 post-mortem: FETCH ~= AT size -> the paired dst[0]/dst[1] stores each wrote a
// strided 16-of-32B pattern (partial lines -> write-allocate RFO).  v3:
//   - 16 lanes per node (4 nodes/wave, 32 nodes/block): one edge row = ONE dwordx4
//     wave-load (16x16B = full 256B row; was two), wave tail = max of 4 Poisson(2)
//   - AT store: lane-contiguous 16B -> 1KB full-line wave-stores, NO RFO
//   - nontemporal AT stores: don't evict xgb from L2 with a 100MB single-use stream
// Per-feature fp32 add order unchanged -> bit-identical numerics.
__global__ __launch_bounds__(512, 8) void gather_cells(
    const unsigned int* __restrict__ xgb, const int* __restrict__ esrc,
    const int* __restrict__ off, unsigned int* __restrict__ AT) {

    int bid = blockIdx.x;                    // r * GNB + tb
    int r = bid / GNB, tb = bid - r * GNB;
    int n0 = tb * 32;
    int tid = threadIdx.x;
    int w = tid >> 6, l = tid & 63;
    int g = l >> 4, qq = l & 15;             // group(node), row-sixteenth (4 dwords)
    int nl = 4 * w + g;                      // block-local node 0..31
    int node = n0 + nl;

    float sA[8];
#pragma unroll
    for (int i = 0; i < 8; ++i) sA[i] = 0.f;

    int ne = 0;
    if (node < NN) {
        int cell = r * NN + node;
        int o = off[cell];                   // group-broadcast loads
        ne = off[cell + 1] - o;
        int t2 = 0;
        for (; t2 + 2 <= ne; t2 += 2) {
            int s0 = esrc[o + t2], s1 = esrc[o + t2 + 1];
            uint4 A = *(const uint4*)(xgb + (size_t)s0 * 64 + qq * 4);
            uint4 B = *(const uint4*)(xgb + (size_t)s1 * 64 + qq * 4);
            upadd8(sA, A);
            upadd8(sA, B);
        }
        if (t2 < ne) {
            uint4 A = *(const uint4*)(xgb + (size_t)esrc[o + t2] * 64 + qq * 4);
            upadd8(sA, A);
        }
    }
    float sc = 1.0f / (float)max(ne, 1);

    u32x4 ob;
    ob.x = packbf2(sA[0] * sc, sA[1] * sc);
    ob.y = packbf2(sA[2] * sc, sA[3] * sc);
    ob.z = packbf2(sA[4] * sc, sA[5] * sc);
    ob.w = packbf2(sA[6] * sc, sA[7] * sc);
    // AT layout: [r*NBLK + 64-tile][node-in-tile][kp]; this block covers 32 nodes
    unsigned int* dst = AT + (((size_t)(r * NBLK + (n0 >> 6))) << 12)
                           + ((n0 & 63) + nl) * 64 + qq * 4;
    __builtin_nontemporal_store(ob, (u32x4*)dst);
}

// ---------------- GEMM kernel: AT -> MT copy + verified MFMA/root/epilogue ----------------
// AT reads are nontemporal (single-use 100MB stream; keep L2 for Wb/xgb).
// MFMA/root/epilogue byte-identical to the verified kernel.
template <int RELU, int WRITEF, int WRITEB>
__global__ __launch_bounds__(512, 4) void gemm_fused(
    const unsigned int* __restrict__ xgb, const unsigned int* __restrict__ AT,
    const unsigned int* __restrict__ Wb, const unsigned int* __restrict__ rootb,
    const float* __restrict__ bias, float* __restrict__ outf,
    unsigned int* __restrict__ outb) {

    __shared__ unsigned int SH[8320];        // 33280 B (MT uses 4288, OF 8320)
    unsigned int* MT = SH;

    int tid = threadIdx.x;
    int tb = blockIdx.x;
    int n0 = tb * TILE_N;
    int e = tid & 63, q = tid >> 6;
    int w = q, l = e;
    int quad = l >> 4, li = l & 15;
    int b = w >> 2;
    int nloc = (w & 3) * 16 + li;
    int g2 = l >> 3, q2 = l & 7, nl2 = 8 * w + g2;   // group mapping for copies

    f32x4 acc[4];
    {
        float bb = bias[16 * w + li];
#pragma unroll
        for (int mt = 0; mt < 4; ++mt) {
            acc[mt][0] = bb; acc[mt][1] = bb; acc[mt][2] = bb; acc[mt][3] = bb;
        }
    }

#define MFMA_BLOCK(rr) do {                                                           \
    const uint4* WbB = (const uint4*)(Wb + (((size_t)(rr) * 2 + b) * 64) * 32);       \
    _Pragma("unroll") for (int kc = 0; kc < 2; ++kc) {                                \
        ABu bf; bf.q = WbB[nloc * 8 + 4 * kc + quad];                                 \
        _Pragma("unroll") for (int mt = 0; mt < 4; ++mt) {                            \
            ABu af; int base_ = (32 * b + 16 * kc + 4 * quad) * 67 + 16 * mt + li;    \
            af.q.x = MT[base_];       af.q.y = MT[base_ + 67];                        \
            af.q.z = MT[base_ + 134]; af.q.w = MT[base_ + 201];                       \
            acc[mt] = __builtin_amdgcn_mfma_f32_16x16x32_bf16(af.v, bf.v, acc[mt], 0, 0, 0); \
        } } } while (0)

#pragma unroll
    for (int r = 0; r < RR; ++r) {
        // coalesced AT tile load (group mapping, nontemporal): issued before barrier,
        // hides under mfma(r-1) of the other waves
        const u32x4* at = (const u32x4*)(AT + (((size_t)(r * NBLK + tb)) << 12) + nl2 * 64 + q2 * 8);
        u32x4 X0 = __builtin_nontemporal_load(at);
        u32x4 X1 = __builtin_nontemporal_load(at + 1);

        __syncthreads();                     // mfma(r-1) readers done with MT
        MT[(8 * q2 + 0) * 67 + nl2] = X0.x;
        MT[(8 * q2 + 1) * 67 + nl2] = X0.y;
        MT[(8 * q2 + 2) * 67 + nl2] = X0.z;
        MT[(8 * q2 + 3) * 67 + nl2] = X0.w;
        MT[(8 * q2 + 4) * 67 + nl2] = X1.x;
        MT[(8 * q2 + 5) * 67 + nl2] = X1.y;
        MT[(8 * q2 + 6) * 67 + nl2] = X1.z;
        MT[(8 * q2 + 7) * 67 + nl2] = X1.w;
        __syncthreads();
        MFMA_BLOCK(r);
    }
    __syncthreads();     // all waves done mfma(7) before MT overwrite

    // ---- root term: MT <- own row (group mapping, coalesced xgb reads) ----
    {
        int nodeg = n0 + nl2;
        if (nodeg < NN) {
            const uint4* xr = (const uint4*)(xgb + (size_t)nodeg * 64 + q2 * 8);
            uint4 X0 = xr[0], X1 = xr[1];
            MT[(8 * q2 + 0) * 67 + nl2] = X0.x;
            MT[(8 * q2 + 1) * 67 + nl2] = X0.y;
            MT[(8 * q2 + 2) * 67 + nl2] = X0.z;
            MT[(8 * q2 + 3) * 67 + nl2] = X0.w;
            MT[(8 * q2 + 4) * 67 + nl2] = X1.x;
            MT[(8 * q2 + 5) * 67 + nl2] = X1.y;
            MT[(8 * q2 + 6) * 67 + nl2] = X1.z;
            MT[(8 * q2 + 7) * 67 + nl2] = X1.w;
        } else {
#pragma unroll
            for (int i = 0; i < 8; ++i) MT[(8 * q2 + i) * 67 + nl2] = 0u;
        }
    }
    __syncthreads();

    // root GEMM: K=128 -> 4 k-chunks, 16 mfma/wave
    const uint4* RbB = (const uint4*)rootb;
#pragma unroll
    for (int kc = 0; kc < 4; ++kc) {
        ABu bf;
        bf.q = RbB[(16 * w + li) * 16 + 4 * kc + quad];
#pragma unroll
        for (int mt = 0; mt < 4; ++mt) {
            ABu af;
            int base = (16 * kc + 4 * quad) * 67 + 16 * mt + li;
            af.q.x = MT[base]; af.q.y = MT[base + 67];
            af.q.z = MT[base + 134]; af.q.w = MT[base + 201];
            acc[mt] = __builtin_amdgcn_mfma_f32_16x16x32_bf16(af.v, bf.v, acc[mt], 0, 0, 0);
        }
    }
    __syncthreads();

    // ---- epilogue: stage D to LDS (fp32, stride 130), then coalesced stores ----
    float* OF = (float*)SH;
#pragma unroll
    for (int mt = 0; mt < 4; ++mt)
#pragma unroll
        for (int reg = 0; reg < 4; ++reg)
            OF[(16 * mt + 4 * quad + reg) * 130 + 16 * w + li] = acc[mt][reg];
    __syncthreads();

    if (WRITEB) {
        int p = tid & 63, rg = tid >> 6;     // pair-col, row-group (8 rows/pass)
#pragma unroll 4
        for (int it = 0; it < 8; ++it) {
            int ee = it * 8 + rg, row = n0 + ee;
            if (row < NN) {
                float v0 = OF[ee * 130 + 2 * p], v1 = OF[ee * 130 + 2 * p + 1];
                if (RELU) { v0 = fmaxf(v0, 0.f); v1 = fmaxf(v1, 0.f); }
                outb[(size_t)row * 64 + p] = packbf2(v0, v1);
            }
        }
    }
    if (WRITEF) {
        int d4 = (tid & 31) * 4, rg = tid >> 5;   // 16 rows/pass
#pragma unroll 4
        for (int it = 0; it < 4; ++it) {
            int ee = it * 16 + rg, row = n0 + ee;
            if (row < NN) {
                float4 v = make_float4(OF[ee * 130 + d4], OF[ee * 130 + d4 + 1],
                                       OF[ee * 130 + d4 + 2], OF[ee * 130 + d4 + 3]);
                if (RELU) {
                    v.x = fmaxf(v.x, 0.f); v.y = fmaxf(v.y, 0.f);
                    v.z = fmaxf(v.z, 0.f); v.w = fmaxf(v.w, 0.f);
                }
                *(float4*)(outf + (size_t)row * DD + d4) = v;
            }
        }
    }
#undef MFMA_BLOCK
}

// ---------------- driver ----------------

extern "C" void kernel_launch(void* const* d_in, const int* in_sizes, int n_in,
                              void* d_out, int out_size, void* d_ws, size_t ws_size,
                              hipStream_t stream) {
    const float* x     = (const float*)d_in[0];
    const int*   ei    = (const int*)d_in[1];
    const int*   src   = ei;
    const int*   dstp  = ei + EE;
    const int*   et    = (const int*)d_in[2];
    const float* W1    = (const float*)d_in[3];
    const float* root1 = (const float*)d_in[4];
    const float* b1    = (const float*)d_in[5];
    const float* W2    = (const float*)d_in[6];
    const float* root2 = (const float*)d_in[7];
    const float* b2    = (const float*)d_in[8];
    float* out = (float*)d_out;

    // ws layout (4 B elements)
    unsigned int* xb  = (unsigned int*)d_ws;         // NN*64 packed bf16 pairs
    unsigned int* hb  = xb + (size_t)NN * 64;        // NN*64
    int* cnt  = (int*)(hb + (size_t)NN * 64);        // CELLS
    int* off  = cnt + CELLS;                         // CELLS + 1
    int* cur  = off + CELLS + 1;                     // CELLS
    int* bsum = cur + CELLS;                         // 512
    int* esrc = bsum + 512;                          // EE
    unsigned int* Wb1 = (unsigned int*)(esrc + EE);  // 32768
    unsigned int* Wb2 = Wb1 + 32768;                 // 32768
    unsigned int* rb1 = Wb2 + 32768;                 // 8192
    unsigned int* rb2 = rb1 + 8192;                  // 8192
    unsigned int* AT  = rb2 + 8192;                  // 8*NBLK*4096 = 25.6M uints (102.4MB)

    hipMemsetAsync(cnt, 0, CELLS * sizeof(int), stream);
    prep_fused<<<NB_A + NB_B + NB_C + NB_D, 256, 0, stream>>>(
        x, xb, W1, W2, Wb1, Wb2, root1, root2, rb1, rb2, dstp, et, cnt);
    scan1<<<SCAN_BLOCKS, 256, 0, stream>>>(cnt, off, bsum);
    scan3<<<SCAN_BLOCKS, 256, 0, stream>>>(off, bsum, cur);
    cell_scatter<<<(EE + 255) / 256, 256, 0, stream>>>(src, dstp, et, cur, esrc);

    // layer 1: gather (full-occupancy) then GEMM; bf16 h out
    gather_cells<<<RR * GNB, 512, 0, stream>>>(xb, esrc, off, AT);
    gemm_fused<1, 0, 1><<<NBLK, 512, 0, stream>>>(xb, AT, Wb1, rb1, b1, nullptr, hb);
    // layer 2: fp32 out
    gather_cells<<<RR * GNB, 512, 0, stream>>>(hb, esrc, off, AT);
    gemm_fused<0, 1, 0><<<NBLK, 512, 0, stream>>>(hb, AT, Wb2, rb2, b2, out, nullptr);
}

// Round 13
// 328.827 us; speedup vs baseline: 1.1157x; 1.1157x over previous
//
#include <hip/hip_runtime.h>

#define NN 50000
#define EE 800000
#define DD 128
#define RR 8
#define CELLS (NN * RR)            // 400000 (rel, dst) cells, key = rel*NN + dst (REL-MAJOR)
#define TILE_N 64
#define NBLK ((NN + TILE_N - 1) / TILE_N)          // 782
#define SCAN_CHUNK 1024
#define SCAN_BLOCKS ((CELLS + SCAN_CHUNK - 1) / SCAN_CHUNK)   // 391
#define ECHUNKS ((EE + 2047) / 2048)               // 391 edge chunks of 2048
#define NB_COLOR (ECHUNKS * 8)                     // 3128 colored blocks

typedef __attribute__((ext_vector_type(4))) float f32x4;
typedef __attribute__((ext_vector_type(8))) short s16x8;
union ABu { uint4 q; s16x8 v; };

// ---------------- bf16 helpers ----------------

__device__ __forceinline__ unsigned int packbf2(float a, float b) {
    unsigned int ua = __float_as_uint(a);
    unsigned int ub = __float_as_uint(b);
    ua = (ua + 0x7fffu + ((ua >> 16) & 1u)) >> 16;           // RNE, low half
    ub = (ub + 0x7fffu + ((ub >> 16) & 1u)) & 0xffff0000u;   // RNE, high half
    return ua | ub;
}

// unpack 2 uint4 (16 bf16) and add into sA[0..15]
__device__ __forceinline__ void upadd16(float* sA, uint4 a, uint4 b) {
    unsigned int u[8] = {a.x, a.y, a.z, a.w, b.x, b.y, b.z, b.w};
#pragma unroll
    for (int j = 0; j < 8; ++j) {
        sA[2 * j]     += __uint_as_float(u[j] << 16);
        sA[2 * j + 1] += __uint_as_float(u[j] & 0xffff0000u);
    }
}

// ---------------- fused prep: to_bf16 + wpack + rpack + count_cells(colored) ----------------
#define NB_A ((NN * 32 + 255) / 256)    // 6250: x -> packed bf16 (float4 -> uint2)
#define NB_B 128                        // wpack: 32768 items
#define NB_C 32                         // rpack: 8192 items

// count_cells coloring: block color c=(idx&7) handles only edges with ((dst>>6)&7)==c.
// With bid%8 -> XCD round-robin, each cnt line is touched by ONE XCD: L2-local atomics,
// single writeback (R10 post-mortem: cross-XCD line ping-pong was the scatter cost).
__global__ void prep_fused(const float* __restrict__ x, unsigned int* __restrict__ xb,
                           const float* __restrict__ W1, const float* __restrict__ W2,
                           unsigned int* __restrict__ Wb1, unsigned int* __restrict__ Wb2,
                           const float* __restrict__ r1, const float* __restrict__ r2,
                           unsigned int* __restrict__ rb1, unsigned int* __restrict__ rb2,
                           const int* __restrict__ dst, const int* __restrict__ et,
                           int* __restrict__ cnt) {
    int bid = blockIdx.x, tid = threadIdx.x;
    if (bid < NB_A) {
        int i = bid * 256 + tid;
        if (i < NN * 32) {
            float4 v = ((const float4*)x)[i];
            ((uint2*)xb)[i] = make_uint2(packbf2(v.x, v.y), packbf2(v.z, v.w));
        }
    } else if (bid < NB_A + NB_B) {
        // W [16 blocks of 64x64, row-major (k,n)] -> Wb [block][n][kp]
        int i = (bid - NB_A) * 256 + tid;
        int n = i & 63, kp = (i >> 6) & 31, rb = i >> 11;
        int s0 = (rb * 64 + 2 * kp) * 64 + n;
        int s1 = (rb * 64 + 2 * kp + 1) * 64 + n;
        Wb1[((rb * 64 + n) * 32) + kp] = packbf2(W1[s0], W1[s1]);
        Wb2[((rb * 64 + n) * 32) + kp] = packbf2(W2[s0], W2[s1]);
    } else if (bid < NB_A + NB_B + NB_C) {
        // root [128k x 128n] -> rb [n][kp]
        int i = (bid - NB_A - NB_B) * 256 + tid;
        int n = i & 127, kp = i >> 7;
        int s0 = (2 * kp) * 128 + n, s1 = (2 * kp + 1) * 128 + n;
        rb1[n * 64 + kp] = packbf2(r1[s0], r1[s1]);
        rb2[n * 64 + kp] = packbf2(r2[s0], r2[s1]);
    } else {
        int idx = bid - NB_A - NB_B - NB_C;    // 0 .. NB_COLOR-1
        int color = idx & 7, chunk = idx >> 3;
        int base_e = chunk * 2048 + tid;
#pragma unroll
        for (int i = 0; i < 8; ++i) {
            int e = base_e + i * 256;
            if (e < EE) {
                int d = dst[e];
                if (((d >> 6) & 7) == color)
                    atomicAdd(&cnt[et[e] * NN + d], 1);
            }
        }
    }
}

// ---------------- prep: scans + scatter (CSR by cell = rel*NN + dst) ----------------

__global__ __launch_bounds__(256) void scan1(const int* __restrict__ cnt,
                                             int* __restrict__ off, int* __restrict__ bsum) {
    __shared__ int s[256];
    int tid = threadIdx.x;
    int base = blockIdx.x * SCAN_CHUNK + tid * 4;
    int v[4];
#pragma unroll
    for (int i = 0; i < 4; ++i) v[i] = (base + i < CELLS) ? cnt[base + i] : 0;
    int tot = v[0] + v[1] + v[2] + v[3];
    s[tid] = tot;
    __syncthreads();
    for (int d = 1; d < 256; d <<= 1) {
        int t = (tid >= d) ? s[tid - d] : 0;
        __syncthreads();
        s[tid] += t;
        __syncthreads();
    }
    int excl = s[tid] - tot;
    if (tid == 255) bsum[blockIdx.x] = s[255];
    int run = excl;
#pragma unroll
    for (int i = 0; i < 4; ++i) {
        if (base + i < CELLS) off[base + i] = run;
        run += v[i];
    }
}

// merged scan2+scan3: each block reduces its own chunk-prefix from bsum, then finalizes
__global__ __launch_bounds__(256) void scan3(int* __restrict__ off, const int* __restrict__ bsum,
                                             int* __restrict__ cur) {
    __shared__ int red[256];
    int tid = threadIdx.x, bid = blockIdx.x;
    int a = 0;
    for (int i = tid; i < bid; i += 256) a += bsum[i];
    red[tid] = a;
    __syncthreads();
#pragma unroll
    for (int d = 128; d > 0; d >>= 1) {
        if (tid < d) red[tid] += red[tid + d];
        __syncthreads();
    }
    int add = red[0];
    int base = bid * SCAN_CHUNK + tid * 4;
#pragma unroll
    for (int i = 0; i < 4; ++i) {
        int c = base + i;
        if (c < CELLS) {
            int o = off[c] + add;
            off[c] = o;
            cur[c] = o;
        }
    }
    if (bid == 0 && tid == 0) off[CELLS] = EE;   // sentinel
}

// colored scatter: block color c=(bid&7) handles edges with ((dst>>6)&7)==c over a
// 2048-edge chunk (bid>>3).  64-node color granule >= esrc/cur line span -> each
// esrc/cur line written+atomized by ONE XCD (bid%8 round-robin): single writeback,
// L2-local atomics.  Cost: 8x coalesced dst re-reads (25.6MB, L3-cached) - cheap.
__global__ void cell_scatter(const int* __restrict__ src, const int* __restrict__ dst,
                             const int* __restrict__ et, int* __restrict__ cur,
                             int* __restrict__ esrc) {
    int idx = blockIdx.x;
    int color = idx & 7, chunk = idx >> 3;
    int base_e = chunk * 2048 + threadIdx.x;
#pragma unroll
    for (int i = 0; i < 8; ++i) {
        int e = base_e + i * 256;
        if (e < EE) {
            int d = dst[e];
            if (((d >> 6) & 7) == color) {
                int cell = et[e] * NN + d;
                int pos = atomicAdd(&cur[cell], 1);
                esrc[pos] = src[e];
            }
        }
    }
}

// ---------------- standalone gather (R10-verified): 8-lane-group-per-node ----------------
__global__ __launch_bounds__(512, 8) void gather_cells(
    const unsigned int* __restrict__ xgb, const int* __restrict__ esrc,
    const int* __restrict__ off, unsigned int* __restrict__ AT) {

    int bid = blockIdx.x;                    // r * NBLK + tb
    int r = bid / NBLK, tb = bid - r * NBLK;
    int n0 = tb * TILE_N;
    int tid = threadIdx.x;
    int w = tid >> 6, l = tid & 63;
    int g = l >> 3, qq = l & 7;              // group(node), row-eighth (8 dwords)
    int nl = 8 * w + g;                      // tile-local node
    int node = n0 + nl;

    float sA[16];
#pragma unroll
    for (int i = 0; i < 16; ++i) sA[i] = 0.f;

    int ne = 0;
    if (node < NN) {
        int cell = r * NN + node;
        int o = off[cell];                   // group-broadcast loads
        ne = off[cell + 1] - o;
        int t2 = 0;
        for (; t2 + 2 <= ne; t2 += 2) {
            int s0 = esrc[o + t2], s1 = esrc[o + t2 + 1];     // group-broadcast
            const uint4* p0 = (const uint4*)(xgb + (size_t)s0 * 64 + qq * 8);
            const uint4* p1 = (const uint4*)(xgb + (size_t)s1 * 64 + qq * 8);
            uint4 A0 = p0[0], A1 = p0[1];
            uint4 B0 = p1[0], B1 = p1[1];
            upadd16(sA, A0, A1);
            upadd16(sA, B0, B1);
        }
        if (t2 < ne) {
            int s0 = esrc[o + t2];
            const uint4* p0 = (const uint4*)(xgb + (size_t)s0 * 64 + qq * 8);
            uint4 A0 = p0[0], A1 = p0[1];
            upadd16(sA, A0, A1);
        }
    }
    float sc = 1.0f / (float)max(ne, 1);

    unsigned int ob[8];
#pragma unroll
    for (int i = 0; i < 8; ++i) ob[i] = packbf2(sA[2 * i] * sc, sA[2 * i + 1] * sc);
    uint4* dst = (uint4*)(AT + ((size_t)bid << 12) + nl * 64 + qq * 8);
    dst[0] = make_uint4(ob[0], ob[1], ob[2], ob[3]);
    dst[1] = make_uint4(ob[4], ob[5], ob[6], ob[7]);
}

// ---------------- GEMM kernel (R10-verified): AT -> MT copy + MFMA/root/epilogue ----------------
template <int RELU, int WRITEF, int WRITEB>
__global__ __launch_bounds__(512, 4) void gemm_fused(
    const unsigned int* __restrict__ xgb, const unsigned int* __restrict__ AT,
    const unsigned int* __restrict__ Wb, const unsigned int* __restrict__ rootb,
    const float* __restrict__ bias, float* __restrict__ outf,
    unsigned int* __restrict__ outb) {

    __shared__ unsigned int SH[8320];        // 33280 B (MT uses 4288, OF 8320)
    unsigned int* MT = SH;

    int tid = threadIdx.x;
    int tb = blockIdx.x;
    int n0 = tb * TILE_N;
    int e = tid & 63, q = tid >> 6;
    int w = q, l = e;
    int quad = l >> 4, li = l & 15;
    int b = w >> 2;
    int nloc = (w & 3) * 16 + li;
    int g2 = l >> 3, q2 = l & 7, nl2 = 8 * w + g2;   // group mapping for copies

    f32x4 acc[4];
    {
        float bb = bias[16 * w + li];
#pragma unroll
        for (int mt = 0; mt < 4; ++mt) {
            acc[mt][0] = bb; acc[mt][1] = bb; acc[mt][2] = bb; acc[mt][3] = bb;
        }
    }

#define MFMA_BLOCK(rr) do {                                                           \
    const uint4* WbB = (const uint4*)(Wb + (((size_t)(rr) * 2 + b) * 64) * 32);       \
    _Pragma("unroll") for (int kc = 0; kc < 2; ++kc) {                                \
        ABu bf; bf.q = WbB[nloc * 8 + 4 * kc + quad];                                 \
        _Pragma("unroll") for (int mt = 0; mt < 4; ++mt) {                            \
            ABu af; int base_ = (32 * b + 16 * kc + 4 * quad) * 67 + 16 * mt + li;    \
            af.q.x = MT[base_];       af.q.y = MT[base_ + 67];                        \
            af.q.z = MT[base_ + 134]; af.q.w = MT[base_ + 201];                       \
            acc[mt] = __builtin_amdgcn_mfma_f32_16x16x32_bf16(af.v, bf.v, acc[mt], 0, 0, 0); \
        } } } while (0)

#pragma unroll
    for (int r = 0; r < RR; ++r) {
        // coalesced AT tile load (group mapping): issued before barrier, hides
        // under mfma(r-1) of the other waves
        const uint4* at = (const uint4*)(AT + (((size_t)(r * NBLK + tb)) << 12) + nl2 * 64 + q2 * 8);
        uint4 X0 = at[0], X1 = at[1];

        __syncthreads();                     // mfma(r-1) readers done with MT
        MT[(8 * q2 + 0) * 67 + nl2] = X0.x;
        MT[(8 * q2 + 1) * 67 + nl2] = X0.y;
        MT[(8 * q2 + 2) * 67 + nl2] = X0.z;
        MT[(8 * q2 + 3) * 67 + nl2] = X0.w;
        MT[(8 * q2 + 4) * 67 + nl2] = X1.x;
        MT[(8 * q2 + 5) * 67 + nl2] = X1.y;
        MT[(8 * q2 + 6) * 67 + nl2] = X1.z;
        MT[(8 * q2 + 7) * 67 + nl2] = X1.w;
        __syncthreads();
        MFMA_BLOCK(r);
    }
    __syncthreads();     // all waves done mfma(7) before MT overwrite

    // ---- root term: MT <- own row (group mapping, coalesced xgb reads) ----
    {
        int nodeg = n0 + nl2;
        if (nodeg < NN) {
            const uint4* xr = (const uint4*)(xgb + (size_t)nodeg * 64 + q2 * 8);
            uint4 X0 = xr[0], X1 = xr[1];
            MT[(8 * q2 + 0) * 67 + nl2] = X0.x;
            MT[(8 * q2 + 1) * 67 + nl2] = X0.y;
            MT[(8 * q2 + 2) * 67 + nl2] = X0.z;
            MT[(8 * q2 + 3) * 67 + nl2] = X0.w;
            MT[(8 * q2 + 4) * 67 + nl2] = X1.x;
            MT[(8 * q2 + 5) * 67 + nl2] = X1.y;
            MT[(8 * q2 + 6) * 67 + nl2] = X1.z;
            MT[(8 * q2 + 7) * 67 + nl2] = X1.w;
        } else {
#pragma unroll
            for (int i = 0; i < 8; ++i) MT[(8 * q2 + i) * 67 + nl2] = 0u;
        }
    }
    __syncthreads();

    // root GEMM: K=128 -> 4 k-chunks, 16 mfma/wave
    const uint4* RbB = (const uint4*)rootb;
#pragma unroll
    for (int kc = 0; kc < 4; ++kc) {
        ABu bf;
        bf.q = RbB[(16 * w + li) * 16 + 4 * kc + quad];
#pragma unroll
        for (int mt = 0; mt < 4; ++mt) {
            ABu af;
            int base = (16 * kc + 4 * quad) * 67 + 16 * mt + li;
            af.q.x = MT[base]; af.q.y = MT[base + 67];
            af.q.z = MT[base + 134]; af.q.w = MT[base + 201];
            acc[mt] = __builtin_amdgcn_mfma_f32_16x16x32_bf16(af.v, bf.v, acc[mt], 0, 0, 0);
        }
    }
    __syncthreads();

    // ---- epilogue: stage D to LDS (fp32, stride 130), then coalesced stores ----
    float* OF = (float*)SH;
#pragma unroll
    for (int mt = 0; mt < 4; ++mt)
#pragma unroll
        for (int reg = 0; reg < 4; ++reg)
            OF[(16 * mt + 4 * quad + reg) * 130 + 16 * w + li] = acc[mt][reg];
    __syncthreads();

    if (WRITEB) {
        int p = tid & 63, rg = tid >> 6;     // pair-col, row-group (8 rows/pass)
#pragma unroll 4
        for (int it = 0; it < 8; ++it) {
            int ee = it * 8 + rg, row = n0 + ee;
            if (row < NN) {
                float v0 = OF[ee * 130 + 2 * p], v1 = OF[ee * 130 + 2 * p + 1];
                if (RELU) { v0 = fmaxf(v0, 0.f); v1 = fmaxf(v1, 0.f); }
                outb[(size_t)row * 64 + p] = packbf2(v0, v1);
            }
        }
    }
    if (WRITEF) {
        int d4 = (tid & 31) * 4, rg = tid >> 5;   // 16 rows/pass
#pragma unroll 4
        for (int it = 0; it < 4; ++it) {
            int ee = it * 16 + rg, row = n0 + ee;
            if (row < NN) {
                float4 v = make_float4(OF[ee * 130 + d4], OF[ee * 130 + d4 + 1],
                                       OF[ee * 130 + d4 + 2], OF[ee * 130 + d4 + 3]);
                if (RELU) {
                    v.x = fmaxf(v.x, 0.f); v.y = fmaxf(v.y, 0.f);
                    v.z = fmaxf(v.z, 0.f); v.w = fmaxf(v.w, 0.f);
                }
                *(float4*)(outf + (size_t)row * DD + d4) = v;
            }
        }
    }
#undef MFMA_BLOCK
}

// ---------------- driver ----------------

extern "C" void kernel_launch(void* const* d_in, const int* in_sizes, int n_in,
                              void* d_out, int out_size, void* d_ws, size_t ws_size,
                              hipStream_t stream) {
    const float* x     = (const float*)d_in[0];
    const int*   ei    = (const int*)d_in[1];
    const int*   src   = ei;
    const int*   dstp  = ei + EE;
    const int*   et    = (const int*)d_in[2];
    const float* W1    = (const float*)d_in[3];
    const float* root1 = (const float*)d_in[4];
    const float* b1    = (const float*)d_in[5];
    const float* W2    = (const float*)d_in[6];
    const float* root2 = (const float*)d_in[7];
    const float* b2    = (const float*)d_in[8];
    float* out = (float*)d_out;

    // ws layout (4 B elements)
    unsigned int* xb  = (unsigned int*)d_ws;         // NN*64 packed bf16 pairs
    unsigned int* hb  = xb + (size_t)NN * 64;        // NN*64
    int* cnt  = (int*)(hb + (size_t)NN * 64);        // CELLS
    int* off  = cnt + CELLS;                         // CELLS + 1
    int* cur  = off + CELLS + 1;                     // CELLS
    int* bsum = cur + CELLS;                         // 512
    int* esrc = bsum + 512;                          // EE
    unsigned int* Wb1 = (unsigned int*)(esrc + EE);  // 32768
    unsigned int* Wb2 = Wb1 + 32768;                 // 32768
    unsigned int* rb1 = Wb2 + 32768;                 // 8192
    unsigned int* rb2 = rb1 + 8192;                  // 8192
    unsigned int* AT  = rb2 + 8192;                  // 8*NBLK*4096 = 25.6M uints (102.4MB)

    hipMemsetAsync(cnt, 0, CELLS * sizeof(int), stream);
    prep_fused<<<NB_A + NB_B + NB_C + NB_COLOR, 256, 0, stream>>>(
        x, xb, W1, W2, Wb1, Wb2, root1, root2, rb1, rb2, dstp, et, cnt);
    scan1<<<SCAN_BLOCKS, 256, 0, stream>>>(cnt, off, bsum);
    scan3<<<SCAN_BLOCKS, 256, 0, stream>>>(off, bsum, cur);
    cell_scatter<<<NB_COLOR, 256, 0, stream>>>(src, dstp, et, cur, esrc);

    // layer 1: gather (full-occupancy) then GEMM; bf16 h out
    gather_cells<<<RR * NBLK, 512, 0, stream>>>(xb, esrc, off, AT);
    gemm_fused<1, 0, 1><<<NBLK, 512, 0, stream>>>(xb, AT, Wb1, rb1, b1, nullptr, hb);
    // layer 2: fp32 out
    gather_cells<<<RR * NBLK, 512, 0, stream>>>(hb, esrc, off, AT);
    gemm_fused<0, 1, 0><<<NBLK, 512, 0, stream>>>(hb, AT, Wb2, rb2, b2, out, nullptr);
}